// Round 1
// baseline (291.986 us; speedup 1.0000x reference)
//
#include <hip/hip_runtime.h>
#include <stdint.h>

// Problem constants (fixed by reference): b=8, CH=256, hw=64*64=4096, d_qk=32.
constexpr int CHN  = 256;
constexpr int HW   = 4096;
constexpr int QBLK = 64;   // query rows per block (4 waves x 16)
constexpr int KVB  = 64;   // keys per LDS tile
constexpr int KSTR = 40;   // LDS row stride (shorts) for K tile: 32 data + 8 pad
constexpr int VSTR = 72;   // LDS row stride (shorts) for V tile: 64 data + 8 pad

typedef float f32x4  __attribute__((ext_vector_type(4)));
typedef short bf16x8 __attribute__((ext_vector_type(8)));
typedef short s16x4  __attribute__((ext_vector_type(4)));

static __device__ __forceinline__ short f2bf(float f) {
  uint32_t u = __builtin_bit_cast(uint32_t, f);
  u += 0x7FFFu + ((u >> 16) & 1u);   // RNE
  return (short)(u >> 16);
}

// ---- prep: Wt[c][320] = concat(Wv(256), Wq(32), Wk(32)) transposed; bcat[320] ----
__global__ __launch_bounds__(256) void prep_kernel(
    const float* __restrict__ Wq, const float* __restrict__ Wk, const float* __restrict__ Wv,
    const float* __restrict__ bq, const float* __restrict__ bk, const float* __restrict__ bv,
    float* __restrict__ Wt, float* __restrict__ bcat) {
  int idx = blockIdx.x * 256 + threadIdx.x;
  if (idx < 256 * 320) {
    int c = idx / 320, r = idx - c * 320;
    float w = (r < 256) ? Wv[r * 256 + c]
            : (r < 288) ? Wq[(r - 256) * 256 + c]
                        : Wk[(r - 288) * 256 + c];
    Wt[idx] = w;
  }
  if (idx < 320)
    bcat[idx] = (idx < 256) ? bv[idx] : (idx < 288) ? bq[idx - 256] : bk[idx - 288];
}

// ---- proj: q/k/v = W @ x + b, f32 VALU GEMM, bf16 outputs ----
// thread t: column m = t&63 of the m-tile, rows rg*64..rg*64+63 (rg = t>>6, 5 waves).
// W rows wave-uniform -> s_loads via readfirstlane'd pointer.
__global__ __launch_bounds__(320) void proj_kernel(
    const float* __restrict__ x, const float* __restrict__ Wt, const float* __restrict__ bcat,
    short* __restrict__ qw, short* __restrict__ kw, short* __restrict__ vw) {
  __shared__ float xlds[CHN * 64];   // x[:, m0:m0+64] tile, f32, 64 KB
  const int t  = threadIdx.x;
  const int b  = blockIdx.y;
  const int m0 = blockIdx.x * 64;
  const float* xb = x + (size_t)b * CHN * HW + m0;
  for (int idx = t; idx < CHN * 16; idx += 320) {
    int c = idx >> 4, mq = idx & 15;
    *(f32x4*)(xlds + c * 64 + mq * 4) = *(const f32x4*)(xb + (size_t)c * HW + mq * 4);
  }
  __syncthreads();
  const int m  = t & 63;
  const int rg = __builtin_amdgcn_readfirstlane(t >> 6);
  const float* wbase = Wt + rg * 64;
  float acc[64];
#pragma unroll
  for (int r = 0; r < 64; ++r) acc[r] = 0.f;
#pragma unroll 4
  for (int c = 0; c < CHN; ++c) {
    float xv = xlds[c * 64 + m];
    const float* wr = wbase + c * 320;
#pragma unroll
    for (int r = 0; r < 64; ++r) acc[r] = fmaf(wr[r], xv, acc[r]);
  }
  const float* bb = bcat + rg * 64;
  if (rg < 4) {            // V rows: V[b][c][m]
#pragma unroll
    for (int r = 0; r < 64; ++r) {
      int c = rg * 64 + r;
      vw[((size_t)b * CHN + c) * HW + m0 + m] = f2bf(acc[r] + bb[r]);
    }
  } else {                 // Q rows then K rows: [b][n][d] row-major, d=32
#pragma unroll
    for (int r = 0; r < 32; ++r)
      qw[((size_t)b * HW + m0 + m) * 32 + r] = f2bf(acc[r] + bb[r]);
#pragma unroll
    for (int r = 32; r < 64; ++r)
      kw[((size_t)b * HW + m0 + m) * 32 + (r - 32)] = f2bf(acc[r] + bb[r]);
  }
}

// ---- fused flash attention + residual ----
// block: batch b = blockIdx&7 (XCD-aligned), q-tile qt = blockIdx>>3.
// wave wv owns q rows [qbase+16*wv, +16). Swapped QK^T: S^T = mfma(K_frag, Q_frag)
// -> lane holds S[m][q=lane&15]; softmax stats per-lane; P is lane-local for PV A-frag.
__global__ __launch_bounds__(256, 2) void attn_kernel(
    const float* __restrict__ x, const float* __restrict__ gamma,
    const short* __restrict__ qw, const short* __restrict__ kw, const short* __restrict__ vw,
    float* __restrict__ out) {
  __shared__ union alignas(16) {
    struct { short K[QBLK * KSTR]; short V[CHN * VSTR]; } kv;  // 5120 + 36864 B
    float oc[64 * 65];                                          // epilogue overlay
  } sm;

  const int tid  = threadIdx.x;
  const int lane = tid & 63;
  const int wv   = tid >> 6;
  const int ln   = lane & 15;
  const int gp   = lane >> 4;
  const int b    = blockIdx.x & 7;
  const int qt   = blockIdx.x >> 3;
  const int qbase = qt * QBLK;

  const short* qb = qw + (size_t)b * HW * 32;
  const short* kb = kw + (size_t)b * HW * 32;
  const short* vb = vw + (size_t)b * CHN * HW;

  // Q fragment held in regs: B-operand of S^T mfma (col=q=ln, k=d=8*gp+i)
  const bf16x8 qf = *(const bf16x8*)(qb + (size_t)(qbase + wv * 16 + ln) * 32 + gp * 8);

  const f32x4 zv = {0.f, 0.f, 0.f, 0.f};
  f32x4 O[16];
#pragma unroll
  for (int i = 0; i < 16; ++i) O[i] = zv;
  float mrun = -__builtin_inff();
  float lrun = 0.f;

  for (int kv0 = 0; kv0 < HW; kv0 += KVB) {
    // stage K tile: 64 rows x 32 bf16, one b128 per thread
    {
      const int row = tid >> 2, ch = tid & 3;
      *(bf16x8*)(&sm.kv.K[row * KSTR + ch * 8]) =
          *(const bf16x8*)(kb + (size_t)(kv0 + row) * 32 + ch * 8);
    }
    // stage V tile: 256 c-rows x 64 m, permuted so PV B-frag is one b128:
    // m = 32h+16u+4g+r  ->  pos = 32h+8g+4u+r
    {
      const int c0 = tid >> 3, jj = tid & 7;
      const int h = jj >> 2, u = (jj >> 1) & 1, g0 = (jj & 1) * 2;
      const int pos_lo = 32 * h + 8 * g0 + 4 * u;
#pragma unroll
      for (int j = 0; j < 8; ++j) {
        const int c = c0 + j * 32;
        bf16x8 vval = *(const bf16x8*)(vb + (size_t)c * HW + kv0 + jj * 8);
        s16x4 lo = {vval[0], vval[1], vval[2], vval[3]};
        s16x4 hi = {vval[4], vval[5], vval[6], vval[7]};
        *(s16x4*)(&sm.kv.V[c * VSTR + pos_lo])     = lo;
        *(s16x4*)(&sm.kv.V[c * VSTR + pos_lo + 8]) = hi;
      }
    }
    __syncthreads();

    // S^T: 4 sub-tiles of 16 keys; lane holds S[m=16*t2+4*gp+r][q=ln]
    f32x4 st[4];
#pragma unroll
    for (int t2 = 0; t2 < 4; ++t2) {
      bf16x8 kf = *(const bf16x8*)(&sm.kv.K[(t2 * 16 + ln) * KSTR + gp * 8]);
      st[t2] = __builtin_amdgcn_mfma_f32_16x16x32_bf16(kf, qf, zv, 0, 0, 0);
    }

    // online softmax for q = ln (reduce across the 4 16-lane groups)
    float tmax = -__builtin_inff();
#pragma unroll
    for (int t2 = 0; t2 < 4; ++t2)
#pragma unroll
      for (int r = 0; r < 4; ++r) tmax = fmaxf(tmax, st[t2][r]);
    tmax = fmaxf(tmax, __shfl_xor(tmax, 16));
    tmax = fmaxf(tmax, __shfl_xor(tmax, 32));
    const float mnew = fmaxf(mrun, tmax);
    const unsigned long long anyup = __ballot(mnew > mrun);
    const float alpha = __expf(mrun - mnew);   // exactly 1.0 when max unchanged
    float psum = 0.f;
#pragma unroll
    for (int t2 = 0; t2 < 4; ++t2)
#pragma unroll
      for (int r = 0; r < 4; ++r) {
        float p = __expf(st[t2][r] - mnew);
        st[t2][r] = p;
        psum += p;
      }
    psum += __shfl_xor(psum, 16);
    psum += __shfl_xor(psum, 32);
    lrun = lrun * alpha + psum;
    mrun = mnew;
    if (anyup) {           // rescale O only when some row max rose
      float ar[4];
#pragma unroll
      for (int r = 0; r < 4; ++r) ar[r] = __shfl(alpha, gp * 4 + r);
#pragma unroll
      for (int i = 0; i < 16; ++i)
#pragma unroll
        for (int r = 0; r < 4; ++r) O[i][r] *= ar[r];
    }

    // P fragments: lane-local repack, A-operand k-map sigma(g,i)=16*(i>>2)+4g+(i&3)
    bf16x8 pf0, pf1;
#pragma unroll
    for (int i = 0; i < 8; ++i) {
      pf0[i] = f2bf(st[i >> 2][i & 3]);
      pf1[i] = f2bf(st[2 + (i >> 2)][i & 3]);
    }

    // PV: O[q][c] += P @ V, 16 c-tiles x 2 k-halves
#pragma unroll
    for (int ct = 0; ct < 16; ++ct) {
      const short* vr = &sm.kv.V[(ct * 16 + ln) * VSTR + gp * 8];
      bf16x8 vf0 = *(const bf16x8*)(vr);        // m in [0,32)
      bf16x8 vf1 = *(const bf16x8*)(vr + 32);   // m in [32,64)
      O[ct] = __builtin_amdgcn_mfma_f32_16x16x32_bf16(pf0, vf0, O[ct], 0, 0, 0);
      O[ct] = __builtin_amdgcn_mfma_f32_16x16x32_bf16(pf1, vf1, O[ct], 0, 0, 0);
    }
    __syncthreads();
  }

  // epilogue: normalize, transpose via LDS, coalesced residual-add store
  float linv[4];
#pragma unroll
  for (int r = 0; r < 4; ++r) linv[r] = 1.0f / __shfl(lrun, gp * 4 + r);
  const float g0 = gamma[0];

  for (int cc = 0; cc < 4; ++cc) {
    __syncthreads();
#pragma unroll
    for (int j = 0; j < 4; ++j) {
      const int ct = cc * 4 + j;
#pragma unroll
      for (int r = 0; r < 4; ++r)
        sm.oc[(j * 16 + ln) * 65 + (wv * 16 + gp * 4 + r)] = O[ct][r] * linv[r];
    }
    __syncthreads();
#pragma unroll
    for (int rr = 0; rr < 16; ++rr) {
      const int c = cc * 64 + wv * 16 + rr;
      const size_t o = ((size_t)b * CHN + c) * HW + qbase + lane;
      out[o] = x[o] + g0 * sm.oc[(wv * 16 + rr) * 65 + lane];
    }
  }
}

extern "C" void kernel_launch(void* const* d_in, const int* in_sizes, int n_in,
                              void* d_out, int out_size, void* d_ws, size_t ws_size,
                              hipStream_t stream) {
  const float* x     = (const float*)d_in[0];
  const float* Wq    = (const float*)d_in[1];
  const float* bq    = (const float*)d_in[2];
  const float* Wk    = (const float*)d_in[3];
  const float* bk    = (const float*)d_in[4];
  const float* Wv    = (const float*)d_in[5];
  const float* bv    = (const float*)d_in[6];
  const float* gamma = (const float*)d_in[7];
  float* out = (float*)d_out;

  // workspace layout (~20.4 MB): Q 2MB | K 2MB | V 16MB | Wt 320KB | bcat
  char* ws = (char*)d_ws;
  short* qw   = (short*)(ws);
  short* kw   = (short*)(ws + (2u << 20));
  short* vw   = (short*)(ws + (4u << 20));
  float* Wt   = (float*)(ws + (20u << 20));
  float* bcat = (float*)(ws + (20u << 20) + (512u << 10));

  prep_kernel<<<320, 256, 0, stream>>>(Wq, Wk, Wv, bq, bk, bv, Wt, bcat);
  proj_kernel<<<dim3(64, 8), 320, 0, stream>>>(x, Wt, bcat, qw, kw, vw);
  attn_kernel<<<512, 256, 0, stream>>>(x, gamma, qw, kw, vw, out);
}

// Round 2
// 165.142 us; speedup vs baseline: 1.7681x; 1.7681x over previous
//
#include <hip/hip_runtime.h>
#include <stdint.h>

// Problem constants (fixed by reference): b=8, CH=256, hw=64*64=4096, d_qk=32.
constexpr int CHN  = 256;
constexpr int HW   = 4096;
constexpr int QBLK = 64;   // query rows per block (4 waves x 16)
constexpr int KVB  = 64;   // keys per LDS tile
constexpr int KSTR = 40;   // LDS row stride (shorts) for K tile: 32 data + 8 pad
constexpr int VSTR = 72;   // LDS row stride (shorts) for V tile: 64 data + 8 pad

typedef float f32x4  __attribute__((ext_vector_type(4)));
typedef short bf16x8 __attribute__((ext_vector_type(8)));
typedef short s16x4  __attribute__((ext_vector_type(4)));

static __device__ __forceinline__ short f2bf(float f) {
  uint32_t u = __builtin_bit_cast(uint32_t, f);
  u += 0x7FFFu + ((u >> 16) & 1u);   // RNE
  return (short)(u >> 16);
}

// ---- prep: Wb[320][256] bf16 = concat(Wv, Wq, Wk) (already [o][c]); bcat[320] f32 ----
__global__ __launch_bounds__(256) void prep_kernel(
    const float* __restrict__ Wq, const float* __restrict__ Wk, const float* __restrict__ Wv,
    const float* __restrict__ bq, const float* __restrict__ bk, const float* __restrict__ bv,
    short* __restrict__ Wb, float* __restrict__ bcat) {
  int idx = blockIdx.x * 256 + threadIdx.x;
  if (idx < 320 * 256) {
    int r = idx >> 8, c = idx & 255;
    float w = (r < 256) ? Wv[idx]
            : (r < 288) ? Wq[(r - 256) * 256 + c]
                        : Wk[(r - 288) * 256 + c];
    Wb[idx] = f2bf(w);
  }
  if (idx < 320)
    bcat[idx] = (idx < 256) ? bv[idx] : (idx < 288) ? bq[idx - 256] : bk[idx - 288];
}

// ---- proj: qkv = Wb @ x + b via bf16 MFMA, LDS-free ----
// block: (n-tile of 64 spatial cols, batch). 5 waves; wave w owns output rows
// [64w, 64w+64). A-frags from Wb (L2), B-frags straight from x f32 (quarter-wave
// coalesced column-group loads) converted to bf16 in-reg.
__global__ __launch_bounds__(320) void proj_kernel(
    const float* __restrict__ x, const short* __restrict__ Wb, const float* __restrict__ bcat,
    short* __restrict__ qw, short* __restrict__ kw, short* __restrict__ vw) {
  const int t    = threadIdx.x;
  const int b    = blockIdx.y;
  const int n0   = blockIdx.x * 64;
  const int lane = t & 63;
  const int w    = t >> 6;
  const int ln   = lane & 15;
  const int gp   = lane >> 4;

  const float* xb = x + (size_t)b * CHN * HW + n0;
  const short* wbp = Wb + (w * 64 + ln) * 256 + gp * 8;

  const f32x4 zv = {0.f, 0.f, 0.f, 0.f};
  f32x4 acc[4][4];
#pragma unroll
  for (int i = 0; i < 4; ++i)
#pragma unroll
    for (int j = 0; j < 4; ++j) acc[i][j] = zv;

#pragma unroll 2
  for (int ks = 0; ks < 8; ++ks) {
    const int k0 = ks * 32;
    bf16x8 a[4];
#pragma unroll
    for (int i = 0; i < 4; ++i)
      a[i] = *(const bf16x8*)(wbp + i * 16 * 256 + k0);
    bf16x8 bxv[4];
#pragma unroll
    for (int j = 0; j < 4; ++j) {
      const float* xc = xb + (size_t)(k0 + gp * 8) * HW + 16 * j + ln;
#pragma unroll
      for (int e = 0; e < 8; ++e) bxv[j][e] = f2bf(xc[(size_t)e * HW]);
    }
#pragma unroll
    for (int i = 0; i < 4; ++i)
#pragma unroll
      for (int j = 0; j < 4; ++j)
        acc[i][j] = __builtin_amdgcn_mfma_f32_16x16x32_bf16(a[i], bxv[j], acc[i][j], 0, 0, 0);
  }

  // epilogue: o = 64w + 16i + 4gp + r (C/D row), n = n0 + 16j + ln (C/D col)
  if (w < 4) {   // V rows -> vw[b][o][n]
#pragma unroll
    for (int i = 0; i < 4; ++i) {
#pragma unroll
      for (int r = 0; r < 4; ++r) {
        const int o = w * 64 + 16 * i + 4 * gp + r;
        const float bias = bcat[o];
        short* vr = vw + ((size_t)b * CHN + o) * HW + n0 + ln;
#pragma unroll
        for (int j = 0; j < 4; ++j)
          vr[16 * j] = f2bf(acc[i][j][r] + bias);
      }
    }
  } else {       // w == 4: i 0,1 -> Q rows; i 2,3 -> K rows; [b][n][32] layout
#pragma unroll
    for (int j = 0; j < 4; ++j) {
      const size_t nrow = ((size_t)b * HW + n0 + 16 * j + ln) * 32;
#pragma unroll
      for (int i = 0; i < 2; ++i) {
        s16x4 pq, pk;
#pragma unroll
        for (int r = 0; r < 4; ++r) {
          pq[r] = f2bf(acc[i][j][r]     + bcat[256 + 16 * i + 4 * gp + r]);
          pk[r] = f2bf(acc[i + 2][j][r] + bcat[288 + 16 * i + 4 * gp + r]);
        }
        *(s16x4*)(qw + nrow + 16 * i + 4 * gp) = pq;
        *(s16x4*)(kw + nrow + 16 * i + 4 * gp) = pk;
      }
    }
  }
}

// ---- fused flash attention + residual (unchanged from round 1, verified) ----
__global__ __launch_bounds__(256, 2) void attn_kernel(
    const float* __restrict__ x, const float* __restrict__ gamma,
    const short* __restrict__ qw, const short* __restrict__ kw, const short* __restrict__ vw,
    float* __restrict__ out) {
  __shared__ union alignas(16) {
    struct { short K[QBLK * KSTR]; short V[CHN * VSTR]; } kv;  // 5120 + 36864 B
    float oc[64 * 65];                                          // epilogue overlay
  } sm;

  const int tid  = threadIdx.x;
  const int lane = tid & 63;
  const int wv   = tid >> 6;
  const int ln   = lane & 15;
  const int gp   = lane >> 4;
  const int b    = blockIdx.x & 7;
  const int qt   = blockIdx.x >> 3;
  const int qbase = qt * QBLK;

  const short* qb = qw + (size_t)b * HW * 32;
  const short* kb = kw + (size_t)b * HW * 32;
  const short* vb = vw + (size_t)b * CHN * HW;

  // Q fragment held in regs: B-operand of S^T mfma (col=q=ln, k=d=8*gp+i)
  const bf16x8 qf = *(const bf16x8*)(qb + (size_t)(qbase + wv * 16 + ln) * 32 + gp * 8);

  const f32x4 zv = {0.f, 0.f, 0.f, 0.f};
  f32x4 O[16];
#pragma unroll
  for (int i = 0; i < 16; ++i) O[i] = zv;
  float mrun = -__builtin_inff();
  float lrun = 0.f;

  for (int kv0 = 0; kv0 < HW; kv0 += KVB) {
    // stage K tile: 64 rows x 32 bf16, one b128 per thread
    {
      const int row = tid >> 2, ch = tid & 3;
      *(bf16x8*)(&sm.kv.K[row * KSTR + ch * 8]) =
          *(const bf16x8*)(kb + (size_t)(kv0 + row) * 32 + ch * 8);
    }
    // stage V tile: 256 c-rows x 64 m, permuted so PV B-frag is one b128:
    // m = 32h+16u+4g+r  ->  pos = 32h+8g+4u+r
    {
      const int c0 = tid >> 3, jj = tid & 7;
      const int h = jj >> 2, u = (jj >> 1) & 1, g0 = (jj & 1) * 2;
      const int pos_lo = 32 * h + 8 * g0 + 4 * u;
#pragma unroll
      for (int j = 0; j < 8; ++j) {
        const int c = c0 + j * 32;
        bf16x8 vval = *(const bf16x8*)(vb + (size_t)c * HW + kv0 + jj * 8);
        s16x4 lo = {vval[0], vval[1], vval[2], vval[3]};
        s16x4 hi = {vval[4], vval[5], vval[6], vval[7]};
        *(s16x4*)(&sm.kv.V[c * VSTR + pos_lo])     = lo;
        *(s16x4*)(&sm.kv.V[c * VSTR + pos_lo + 8]) = hi;
      }
    }
    __syncthreads();

    // S^T: 4 sub-tiles of 16 keys; lane holds S[m=16*t2+4*gp+r][q=ln]
    f32x4 st[4];
#pragma unroll
    for (int t2 = 0; t2 < 4; ++t2) {
      bf16x8 kf = *(const bf16x8*)(&sm.kv.K[(t2 * 16 + ln) * KSTR + gp * 8]);
      st[t2] = __builtin_amdgcn_mfma_f32_16x16x32_bf16(kf, qf, zv, 0, 0, 0);
    }

    // online softmax for q = ln (reduce across the 4 16-lane groups)
    float tmax = -__builtin_inff();
#pragma unroll
    for (int t2 = 0; t2 < 4; ++t2)
#pragma unroll
      for (int r = 0; r < 4; ++r) tmax = fmaxf(tmax, st[t2][r]);
    tmax = fmaxf(tmax, __shfl_xor(tmax, 16));
    tmax = fmaxf(tmax, __shfl_xor(tmax, 32));
    const float mnew = fmaxf(mrun, tmax);
    const unsigned long long anyup = __ballot(mnew > mrun);
    const float alpha = __expf(mrun - mnew);   // exactly 1.0 when max unchanged
    float psum = 0.f;
#pragma unroll
    for (int t2 = 0; t2 < 4; ++t2)
#pragma unroll
      for (int r = 0; r < 4; ++r) {
        float p = __expf(st[t2][r] - mnew);
        st[t2][r] = p;
        psum += p;
      }
    psum += __shfl_xor(psum, 16);
    psum += __shfl_xor(psum, 32);
    lrun = lrun * alpha + psum;
    mrun = mnew;
    if (anyup) {           // rescale O only when some row max rose
      float ar[4];
#pragma unroll
      for (int r = 0; r < 4; ++r) ar[r] = __shfl(alpha, gp * 4 + r);
#pragma unroll
      for (int i = 0; i < 16; ++i)
#pragma unroll
        for (int r = 0; r < 4; ++r) O[i][r] *= ar[r];
    }

    // P fragments: lane-local repack, A-operand k-map sigma(g,i)=16*(i>>2)+4g+(i&3)
    bf16x8 pf0, pf1;
#pragma unroll
    for (int i = 0; i < 8; ++i) {
      pf0[i] = f2bf(st[i >> 2][i & 3]);
      pf1[i] = f2bf(st[2 + (i >> 2)][i & 3]);
    }

    // PV: O[q][c] += P @ V, 16 c-tiles x 2 k-halves
#pragma unroll
    for (int ct = 0; ct < 16; ++ct) {
      const short* vr = &sm.kv.V[(ct * 16 + ln) * VSTR + gp * 8];
      bf16x8 vf0 = *(const bf16x8*)(vr);        // m in [0,32)
      bf16x8 vf1 = *(const bf16x8*)(vr + 32);   // m in [32,64)
      O[ct] = __builtin_amdgcn_mfma_f32_16x16x32_bf16(pf0, vf0, O[ct], 0, 0, 0);
      O[ct] = __builtin_amdgcn_mfma_f32_16x16x32_bf16(pf1, vf1, O[ct], 0, 0, 0);
    }
    __syncthreads();
  }

  // epilogue: normalize, transpose via LDS, coalesced residual-add store
  float linv[4];
#pragma unroll
  for (int r = 0; r < 4; ++r) linv[r] = 1.0f / __shfl(lrun, gp * 4 + r);
  const float g0 = gamma[0];

  for (int cc = 0; cc < 4; ++cc) {
    __syncthreads();
#pragma unroll
    for (int j = 0; j < 4; ++j) {
      const int ct = cc * 4 + j;
#pragma unroll
      for (int r = 0; r < 4; ++r)
        sm.oc[(j * 16 + ln) * 65 + (wv * 16 + gp * 4 + r)] = O[ct][r] * linv[r];
    }
    __syncthreads();
#pragma unroll
    for (int rr = 0; rr < 16; ++rr) {
      const int c = cc * 64 + wv * 16 + rr;
      const size_t o = ((size_t)b * CHN + c) * HW + qbase + lane;
      out[o] = x[o] + g0 * sm.oc[(wv * 16 + rr) * 65 + lane];
    }
  }
}

extern "C" void kernel_launch(void* const* d_in, const int* in_sizes, int n_in,
                              void* d_out, int out_size, void* d_ws, size_t ws_size,
                              hipStream_t stream) {
  const float* x     = (const float*)d_in[0];
  const float* Wq    = (const float*)d_in[1];
  const float* bq    = (const float*)d_in[2];
  const float* Wk    = (const float*)d_in[3];
  const float* bk    = (const float*)d_in[4];
  const float* Wv    = (const float*)d_in[5];
  const float* bv    = (const float*)d_in[6];
  const float* gamma = (const float*)d_in[7];
  float* out = (float*)d_out;

  // workspace layout (~20.5 MB): Q 2MB | K 2MB | V 16MB | Wb bf16 160KB | bcat
  char* ws = (char*)d_ws;
  short* qw   = (short*)(ws);
  short* kw   = (short*)(ws + (2u << 20));
  short* vw   = (short*)(ws + (4u << 20));
  short* Wb   = (short*)(ws + (20u << 20));
  float* bcat = (float*)(ws + (20u << 20) + (256u << 10));

  prep_kernel<<<320, 256, 0, stream>>>(Wq, Wk, Wv, bq, bk, bv, Wb, bcat);
  proj_kernel<<<dim3(64, 8), 320, 0, stream>>>(x, Wb, bcat, qw, kw, vw);
  attn_kernel<<<512, 256, 0, stream>>>(x, gamma, qw, kw, vw, out);
}

// Round 3
// 153.746 us; speedup vs baseline: 1.8991x; 1.0741x over previous
//
#include <hip/hip_runtime.h>
#include <stdint.h>

// Problem constants (fixed by reference): b=8, CH=256, hw=64*64=4096, d_qk=32.
constexpr int CHN = 256;
constexpr int HW  = 4096;

typedef float f32x4   __attribute__((ext_vector_type(4)));
typedef float f32x16  __attribute__((ext_vector_type(16)));
typedef short bf16x8  __attribute__((ext_vector_type(8)));
typedef short s16x4   __attribute__((ext_vector_type(4)));
typedef uint32_t u32x4 __attribute__((ext_vector_type(4)));

static __device__ __forceinline__ short f2bf(float f) {
  uint32_t u = __builtin_bit_cast(uint32_t, f);
  u += 0x7FFFu + ((u >> 16) & 1u);   // RNE
  return (short)(u >> 16);
}

// pack 2 f32 -> 2 bf16 in one u32 (lo=a, hi=b); plain VOP3, no trans hazard
static __device__ __forceinline__ uint32_t pkbf(float a, float b) {
  uint32_t r;
  asm("v_cvt_pk_bf16_f32 %0, %1, %2" : "=v"(r) : "v"(a), "v"(b));
  return r;
}

// async global->LDS, 16B per lane; LDS dest is wave-uniform base + lane*16
static __device__ __forceinline__ void gl16(const void* g, void* l) {
  __builtin_amdgcn_global_load_lds(
      (const __attribute__((address_space(1))) uint32_t*)g,
      (__attribute__((address_space(3))) uint32_t*)l, 16, 0, 0);
}

// ---- prep: Wb[320][256] bf16 = concat(Wv, Wq, Wk); bcat[320] f32 ----
__global__ __launch_bounds__(256) void prep_kernel(
    const float* __restrict__ Wq, const float* __restrict__ Wk, const float* __restrict__ Wv,
    const float* __restrict__ bq, const float* __restrict__ bk, const float* __restrict__ bv,
    short* __restrict__ Wb, float* __restrict__ bcat) {
  int idx = blockIdx.x * 256 + threadIdx.x;
  if (idx < 320 * 256) {
    int r = idx >> 8, c = idx & 255;
    float w = (r < 256) ? Wv[idx]
            : (r < 288) ? Wq[(r - 256) * 256 + c]
                        : Wk[(r - 288) * 256 + c];
    Wb[idx] = f2bf(w);
  }
  if (idx < 320)
    bcat[idx] = (idx < 256) ? bv[idx] : (idx < 288) ? bq[idx - 256] : bk[idx - 288];
}

// ---- proj: qkv = Wb @ x + b via bf16 MFMA, LDS-free ----
// V is emitted per 64-column tile, PV-permuted (m bit2<->bit3) and XOR-swizzled
// (short idx ^ ((c&7)<<3)) so attn can stage it with linear global_load_lds and
// read PV B-fragments conflict-free. Q is pre-scaled by log2(e) for exp2 softmax.
__global__ __launch_bounds__(320) void proj_kernel(
    const float* __restrict__ x, const short* __restrict__ Wb, const float* __restrict__ bcat,
    short* __restrict__ qw, short* __restrict__ kw, short* __restrict__ vws) {
  const int t    = threadIdx.x;
  const int b    = blockIdx.y;
  const int n0   = blockIdx.x * 64;
  const int lane = t & 63;
  const int w    = t >> 6;
  const int ln   = lane & 15;
  const int gp   = lane >> 4;

  const float* xb  = x + (size_t)b * CHN * HW + n0;
  const short* wbp = Wb + (w * 64 + ln) * 256 + gp * 8;

  const f32x4 zv = {0.f, 0.f, 0.f, 0.f};
  f32x4 acc[4][4];
#pragma unroll
  for (int i = 0; i < 4; ++i)
#pragma unroll
    for (int j = 0; j < 4; ++j) acc[i][j] = zv;

#pragma unroll 2
  for (int ks = 0; ks < 8; ++ks) {
    const int k0 = ks * 32;
    bf16x8 a[4];
#pragma unroll
    for (int i = 0; i < 4; ++i)
      a[i] = *(const bf16x8*)(wbp + i * 16 * 256 + k0);
    bf16x8 bxv[4];
#pragma unroll
    for (int j = 0; j < 4; ++j) {
      const float* xc = xb + (size_t)(k0 + gp * 8) * HW + 16 * j + ln;
#pragma unroll
      for (int e = 0; e < 8; ++e) bxv[j][e] = f2bf(xc[(size_t)e * HW]);
    }
#pragma unroll
    for (int i = 0; i < 4; ++i)
#pragma unroll
      for (int j = 0; j < 4; ++j)
        acc[i][j] = __builtin_amdgcn_mfma_f32_16x16x32_bf16(a[i], bxv[j], acc[i][j], 0, 0, 0);
  }

  if (w < 4) {   // V rows -> permuted+swizzled tile blob [b][tile][c][pos]
    short* vblob = vws + ((size_t)(b * 64 + blockIdx.x)) * 16384;
    const int ph = 8 * ((ln >> 2) & 1) + 4 * (ln >> 3) + (ln & 3);  // pos within 16-block
#pragma unroll
    for (int i = 0; i < 4; ++i) {
#pragma unroll
      for (int r = 0; r < 4; ++r) {
        const int c = w * 64 + 16 * i + 4 * gp + r;
        const float bias = bcat[c];
        const int sw = (c & 7) << 3;
#pragma unroll
        for (int j = 0; j < 4; ++j)
          vblob[c * 64 + ((16 * j + ph) ^ sw)] = f2bf(acc[i][j][r] + bias);
      }
    }
  } else {       // w == 4: i 0,1 -> Q rows (x log2e); i 2,3 -> K rows; [b][n][32]
    constexpr float LOG2E = 1.44269504088896340736f;
#pragma unroll
    for (int j = 0; j < 4; ++j) {
      const size_t nrow = ((size_t)b * HW + n0 + 16 * j + ln) * 32;
#pragma unroll
      for (int i = 0; i < 2; ++i) {
        s16x4 pq, pk;
#pragma unroll
        for (int r = 0; r < 4; ++r) {
          pq[r] = f2bf((acc[i][j][r] + bcat[256 + 16 * i + 4 * gp + r]) * LOG2E);
          pk[r] = f2bf(acc[i + 2][j][r] + bcat[288 + 16 * i + 4 * gp + r]);
        }
        *(s16x4*)(qw + nrow + 16 * i + 4 * gp) = pq;
        *(s16x4*)(kw + nrow + 16 * i + 4 * gp) = pk;
      }
    }
  }
}

// ---- fused flash attention + residual, 32x32x16 MFMA, 32 q-rows/wave ----
// block: 128 q-rows (4 waves), batch b = blockIdx&7. Swapped QK^T: S^T[m][q],
// softmax per-lane (q = lane&31, both halves duplicate stats). P repacked
// in-register to PV A-frags via v_cvt_pk_bf16_f32; V B-frags from the
// pre-permuted LDS tile. V double-buffered via global_load_lds; K frags from
// L2 (register-prefetched one iter ahead).
__global__ __launch_bounds__(256, 1) void attn_kernel(
    const float* __restrict__ x, const float* __restrict__ gamma,
    const short* __restrict__ qw, const short* __restrict__ kw,
    const short* __restrict__ vws, float* __restrict__ out) {
  __shared__ alignas(16) char sm[2 * 32768];

  const int tid  = threadIdx.x;
  const int lane = tid & 63;
  const int wv   = tid >> 6;
  const int l5   = lane & 31;
  const int h    = lane >> 5;
  const int b    = blockIdx.x & 7;
  const int qt   = blockIdx.x >> 3;
  const int qbase = qt * 128;

  const short* qb    = qw + (size_t)b * HW * 32;
  const short* kb    = kw + (size_t)b * HW * 32;
  const char*  vblob = (const char*)vws + (size_t)b * 64 * 32768;

  // Q fragments (B-operand): q = qbase + wv*32 + l5; k-chunks at {0,16}+h*8
  const short* qrow = qb + (size_t)(qbase + wv * 32 + l5) * 32 + h * 8;
  const bf16x8 qf0 = *(const bf16x8*)(qrow);
  const bf16x8 qf1 = *(const bf16x8*)(qrow + 16);

  f32x16 z16;
#pragma unroll
  for (int r = 0; r < 16; ++r) z16[r] = 0.f;
  f32x16 O[8];
#pragma unroll
  for (int ct = 0; ct < 8; ++ct) O[ct] = z16;

  float mrun = -1e30f, lrun = 0.f;

  // stage tile 0 into sm[0]
  {
    const char* gs = vblob + (wv * 8) * 1024 + lane * 16;
    char* ld = sm + (wv * 8) * 1024;
#pragma unroll
    for (int j = 0; j < 8; ++j) gl16(gs + j * 1024, ld + j * 1024);
  }

  // K fragments for iter 0 (A-operand rows: m = mti*32 + l5)
  const short* kfb = kb + (size_t)l5 * 32 + h * 8;
  bf16x8 kf00 = *(const bf16x8*)(kfb);
  bf16x8 kf01 = *(const bf16x8*)(kfb + 16);
  bf16x8 kf10 = *(const bf16x8*)(kfb + 1024);
  bf16x8 kf11 = *(const bf16x8*)(kfb + 1024 + 16);

  const int swv = (l5 & 7) << 4;   // V read swizzle (bytes), lane-constant

  for (int it = 0; it < 64; ++it) {
    __syncthreads();   // stage(it) drained (vmcnt0) + visible to all waves
    const char* buf = sm + (it & 1) * 32768;
    if (it < 63) {     // issue stage(it+1) into the other buffer
      const char* gs = vblob + (size_t)(it + 1) * 32768 + (wv * 8) * 1024 + lane * 16;
      char* ld = sm + ((it + 1) & 1) * 32768 + (wv * 8) * 1024;
#pragma unroll
      for (int j = 0; j < 8; ++j) gl16(gs + j * 1024, ld + j * 1024);
    }

    // QK^T: S^T[m][q], two 32-m tiles, d=32 in two k-chunks
    f32x16 s0 = __builtin_amdgcn_mfma_f32_32x32x16_bf16(kf00, qf0, z16, 0, 0, 0);
    s0 = __builtin_amdgcn_mfma_f32_32x32x16_bf16(kf01, qf1, s0, 0, 0, 0);
    f32x16 s1 = __builtin_amdgcn_mfma_f32_32x32x16_bf16(kf10, qf0, z16, 0, 0, 0);
    s1 = __builtin_amdgcn_mfma_f32_32x32x16_bf16(kf11, qf1, s1, 0, 0, 0);

    // prefetch next iter's K frags (lands during softmax+PV)
    if (it < 63) {
      const short* kn = kfb + (size_t)(it + 1) * 2048;
      kf00 = *(const bf16x8*)(kn);
      kf01 = *(const bf16x8*)(kn + 16);
      kf10 = *(const bf16x8*)(kn + 1024);
      kf11 = *(const bf16x8*)(kn + 1024 + 16);
    }

    // online softmax in log2 space (Q pre-scaled by log2e), defer-max thr=8
    float tmax = -1e30f;
#pragma unroll
    for (int r = 0; r < 16; ++r) tmax = fmaxf(tmax, fmaxf(s0[r], s1[r]));
    tmax = fmaxf(tmax, __shfl_xor(tmax, 32));
    if (__any(tmax > mrun + 8.f)) {
      const float mnew = fmaxf(mrun, tmax);
      const float al = __builtin_amdgcn_exp2f(mrun - mnew);
      lrun *= al;
      mrun = mnew;
#pragma unroll
      for (int r = 0; r < 16; ++r) {
        const float ar = __shfl(al, (r & 3) + ((r >> 2) << 3) + (h << 2));
#pragma unroll
        for (int ct = 0; ct < 8; ++ct) O[ct][r] *= ar;
      }
    }
    float ps = 0.f;
#pragma unroll
    for (int r = 0; r < 16; ++r) {
      s0[r] = __builtin_amdgcn_exp2f(s0[r] - mrun);
      s1[r] = __builtin_amdgcn_exp2f(s1[r] - mrun);
      ps += s0[r] + s1[r];
    }
    ps += __shfl_xor(ps, 32);
    lrun += ps;

    // PV: 4 m-chunks x 8 c-tiles; P packed in-register, V from swizzled LDS
    const char* vb0 = buf + l5 * 128;
#pragma unroll
    for (int mt = 0; mt < 4; ++mt) {
      const int r0 = (mt & 1) * 8;
      uint32_t w0, w1, w2, w3;
      if (mt < 2) {
        w0 = pkbf(s0[r0 + 0], s0[r0 + 1]); w1 = pkbf(s0[r0 + 2], s0[r0 + 3]);
        w2 = pkbf(s0[r0 + 4], s0[r0 + 5]); w3 = pkbf(s0[r0 + 6], s0[r0 + 7]);
      } else {
        w0 = pkbf(s1[r0 + 0], s1[r0 + 1]); w1 = pkbf(s1[r0 + 2], s1[r0 + 3]);
        w2 = pkbf(s1[r0 + 4], s1[r0 + 5]); w3 = pkbf(s1[r0 + 6], s1[r0 + 7]);
      }
      const u32x4 paw = {w0, w1, w2, w3};
      const bf16x8 pa = __builtin_bit_cast(bf16x8, paw);
      const char* vbm = vb0 + ((32 * mt + 16 * h) ^ swv);
#pragma unroll
      for (int ct = 0; ct < 8; ++ct) {
        const bf16x8 vf = *(const bf16x8*)(vbm + ct * 4096);
        O[ct] = __builtin_amdgcn_mfma_f32_32x32x16_bf16(pa, vf, O[ct], 0, 0, 0);
      }
    }
  }

  // epilogue: fold gamma/l, transpose via LDS, coalesced residual-add store
  const float g0 = gamma[0];
  float linv[16];
#pragma unroll
  for (int r = 0; r < 16; ++r)
    linv[r] = g0 / __shfl(lrun, (r & 3) + ((r >> 2) << 3) + (h << 2));

  float* eo = (float*)sm;   // [32 c][132 q-stride] overlay
  for (int ct = 0; ct < 8; ++ct) {
    __syncthreads();
#pragma unroll
    for (int r = 0; r < 16; ++r)
      eo[l5 * 132 + wv * 32 + ((r & 3) + ((r >> 2) << 3) + (h << 2))] = O[ct][r] * linv[r];
    __syncthreads();
    const int cl = tid >> 3, seg = tid & 7;
    const size_t gi = ((size_t)b * CHN + ct * 32 + cl) * HW + qbase + seg * 16;
#pragma unroll
    for (int u = 0; u < 4; ++u) {
      const f32x4 xv = *(const f32x4*)(x + gi + u * 4);
      const f32x4 ov = *(const f32x4*)(&eo[cl * 132 + seg * 16 + u * 4]);
      *(f32x4*)(out + gi + u * 4) = xv + ov;
    }
  }
}

extern "C" void kernel_launch(void* const* d_in, const int* in_sizes, int n_in,
                              void* d_out, int out_size, void* d_ws, size_t ws_size,
                              hipStream_t stream) {
  const float* x     = (const float*)d_in[0];
  const float* Wq    = (const float*)d_in[1];
  const float* bq    = (const float*)d_in[2];
  const float* Wk    = (const float*)d_in[3];
  const float* bk    = (const float*)d_in[4];
  const float* Wv    = (const float*)d_in[5];
  const float* bv    = (const float*)d_in[6];
  const float* gamma = (const float*)d_in[7];
  float* out = (float*)d_out;

  // workspace: Q 2MB | K 2MB | V blobs 16MB | Wb bf16 160KB | bcat
  char* ws = (char*)d_ws;
  short* qw   = (short*)(ws);
  short* kw   = (short*)(ws + (2u << 20));
  short* vws  = (short*)(ws + (4u << 20));
  short* Wb   = (short*)(ws + (20u << 20));
  float* bcat = (float*)(ws + (20u << 20) + (256u << 10));

  prep_kernel<<<320, 256, 0, stream>>>(Wq, Wk, Wv, bq, bk, bv, Wb, bcat);
  proj_kernel<<<dim3(64, 8), 320, 0, stream>>>(x, Wb, bcat, qw, kw, vws);
  attn_kernel<<<256, 256, 0, stream>>>(x, gamma, qw, kw, vws, out);
}